// Round 19
// baseline (103.869 us; speedup 1.0000x reference)
//
#include <hip/hip_runtime.h>

// Problem constants: N=50000, E=100000, F=80000, B=64, S=32, T=32, D=3
#define NB      64
#define SS      32
#define TT      32
#define RADIUSF 1.1f
#define NC      16              // chunks per graph -> grid = 16*64 = 1024 = 4 blocks/CU
#define NROWS   34              // delta bins: s* in [0,32], s*+1 in [1,33]
#define NCNT    128             // blocks for build pass
#define NRB     64              // extra build blocks for node records
#define BCAP    1440            // max EF items per build slice (180000/128 = 1407)
#define UCAP    4096            // per-graph capacity in U (mean 2812, >20 sigma headroom)

// ---------- k_init: zero reservation counters + node ranges ----------
__global__ __launch_bounds__(256) void k_init(
    const int* __restrict__ batch, int* __restrict__ cur,
    int* __restrict__ ns, int Nn)
{
    const int tid = threadIdx.x;
    if (tid < NB) cur[tid] = 0;
    if (tid <= NB) {
        int lo = 0, hi = Nn;
        while (lo < hi) { const int mid = (lo + hi) >> 1; if (batch[mid] < tid) lo = mid + 1; else hi = mid; }
        ns[tid] = lo;
    }
}

// ---------- k_build: LDS record cache + atomic reservation into U; +NR pack ----------
__global__ __launch_bounds__(256) void k_build(
    const float* __restrict__ x, const float* __restrict__ nw,
    const int* __restrict__ ei, const int* __restrict__ fc,
    const int* __restrict__ batch, int* __restrict__ cur,
    int4* __restrict__ U, float4* __restrict__ NR, int Nn, int E, int F)
{
    const int tid = threadIdx.x;

    if ((int)blockIdx.x >= NCNT) {
        // ---- node records: NR[n] = (x0, x1, x2, nw) ----
        const int blk = blockIdx.x - NCNT;
        const int n0 = (int)((long long)Nn * blk / NRB);
        const int n1 = (int)((long long)Nn * (blk + 1) / NRB);
        for (int n = n0 + tid; n < n1; n += 256)
            NR[n] = make_float4(x[3 * n], x[3 * n + 1], x[3 * n + 2], nw[n]);
        return;
    }

    __shared__ int lc[NB];
    __shared__ int lb[NB];
    __shared__ int   r_i0[BCAP], r_i1[BCAP], r_i2[BCAP];
    __shared__ float r_w[BCAP];
    __shared__ unsigned char r_b[BCAP];
    const int EF = E + F;

    if (tid < NB) lc[tid] = 0;
    __syncthreads();

    const int j0 = (int)((long long)EF * blockIdx.x / NCNT);
    const int j1 = (int)((long long)EF * (blockIdx.x + 1) / NCNT);
    // pass 1: gather once, stash record in LDS, count per bucket (LDS atomics)
    for (int j = j0 + tid, idx = tid; j < j1; j += 256, idx += 256) {
        int i0, i1, i2; float w;
        if (j < E) {
            i0 = ei[j]; i1 = ei[E + j]; i2 = i0;
            w = -fmaxf(nw[i0], nw[i1]);
        } else {
            const int f = j - E;
            i0 = fc[f]; i1 = fc[F + f]; i2 = fc[2 * F + f];
            w = fmaxf(nw[i0], fmaxf(nw[i1], nw[i2]));
        }
        const int b = batch[i0];
        r_i0[idx] = i0; r_i1[idx] = i1; r_i2[idx] = i2;
        r_w[idx] = w; r_b[idx] = (unsigned char)b;
        atomicAdd(&lc[b], 1);
    }
    __syncthreads();
    // reserve a contiguous run per bucket: ONE global atomic per (block,bucket)
    if (tid < NB) { const int c = lc[tid]; lb[tid] = c ? atomicAdd(&cur[tid], c) : 0; lc[tid] = 0; }
    __syncthreads();
    // pass 2: write from LDS records at reserved slots
    const int cnt = j1 - j0;
    for (int idx = tid; idx < cnt; idx += 256) {
        const int b = r_b[idx];
        const int r = atomicAdd(&lc[b], 1);
        U[(b << 12) + lb[b] + r] =
            make_int4(r_i0[idx], r_i1[idx], r_i2[idx], __float_as_int(r_w[idx]));
    }
}

// ---------- k_main2: vec4 node loop; NR-gather EF loop; ds_add_f32 histogram ----------
__global__ __launch_bounds__(256) void k_main2(
    const float* __restrict__ x, const float* __restrict__ nw,
    const float* __restrict__ v, const int4* __restrict__ U,
    const float4* __restrict__ NR, const int* __restrict__ ns,
    const int* __restrict__ cur, float* __restrict__ partial)
{
    __shared__ float hist[4][NROWS * 64];

    const int tid  = threadIdx.x;
    const int wave = tid >> 6;
    const int lane = tid & 63;
    const int t    = lane & 31;
    const int half = lane >> 5;
    const int b     = blockIdx.x & 63;      // XCD-aligned: all chunks of b on XCD b%8
    const int chunk = blockIdx.x >> 6;

    float* H = hist[wave];
    for (int i = tid; i < 4 * NROWS * 64; i += 256) ((float*)hist)[i] = 0.0f;
    __syncthreads();

    // v column for this lane's theta (3 regs)
    const float v0 = v[t], v1 = v[TT + t], v2 = v[2 * TT + t];

    const float INV = 31.0f / 2.2f;
    const float DLT = 2.2f / 31.0f;

    // s* = rint((h+R)/step); sigma* = 1/(1+exp(500*(h - lin[s*])))
    // lane-private column -> ds_add_f32 (no-return, fire-and-forget)
#define BODY(hv, wv)                                                        \
    {                                                                       \
        const float hr = hv + RADIUSF;                                      \
        float sf = rintf(hr * INV);                                         \
        sf = fminf(fmaxf(sf, 0.0f), 32.0f);                                 \
        const float t1 = __builtin_fmaf(sf, -DLT, hr);                      \
        const float Ee = __expf(500.0f * t1);                               \
        const float sg = __builtin_amdgcn_rcpf(1.0f + Ee);                  \
        const float dA = wv * sg;                                           \
        const float dB = wv - dA;                                           \
        float* p = H + (int)sf * 64 + lane;                                 \
        atomicAdd(&p[0], dA);                                               \
        atomicAdd(&p[64], dB);                                              \
    }

    // ---- nodes of graph b: 4 nodes per half-iter via aligned float4 loads ----
    {
        const int g0 = ns[b], g1 = ns[b + 1];
        const int gc = g1 - g0;
        const int m0 = g0 + (int)(((long long)gc * chunk) / NC);
        const int m1 = g0 + (int)(((long long)gc * (chunk + 1)) / NC);
        const int gs = m0 & ~3;                       // 4-aligned base
        for (int g = gs + (wave * 2 + half) * 4; g < m1; g += 32) {
            if (g >= m0 && g + 4 <= m1) {             // fast aligned quad
                const float4* xp = (const float4*)(x + 3 * g);
                const float4 X0 = xp[0], X1 = xp[1], X2 = xp[2];
                const float4 W  = *(const float4*)(nw + g);
                const float ha = __builtin_fmaf(X0.x, v0, __builtin_fmaf(X0.y, v1, X0.z * v2));
                const float hb = __builtin_fmaf(X0.w, v0, __builtin_fmaf(X1.x, v1, X1.y * v2));
                const float hc = __builtin_fmaf(X1.z, v0, __builtin_fmaf(X1.w, v1, X2.x * v2));
                const float hd = __builtin_fmaf(X2.y, v0, __builtin_fmaf(X2.z, v1, X2.w * v2));
                BODY(ha, W.x) BODY(hb, W.y) BODY(hc, W.z) BODY(hd, W.w)
            } else {                                  // head/tail scalar
                const int n_lo = g < m0 ? m0 : g;
                const int n_hi = (g + 4 < m1 ? g + 4 : m1);
                for (int n = n_lo; n < n_hi; ++n) {
                    const float x0 = x[3 * n], x1 = x[3 * n + 1], x2 = x[3 * n + 2];
                    const float h = __builtin_fmaf(x0, v0, __builtin_fmaf(x1, v1, x2 * v2));
                    BODY(h, nw[n])
                }
            }
        }
    }

    // ---- edges+faces of graph b: NR float4 gathers (3 VMEM/simplex); depth-1 prefetch ----
    {
        const int g0 = b << 12;                       // b * UCAP
        const int gc = min(cur[b], UCAP);
        const int m0 = g0 + (int)(((long long)gc * chunk) / NC);
        const int m1 = g0 + (int)(((long long)gc * (chunk + 1)) / NC);
        int k = m0 + wave * 2;
        if (k < m1) {
            int4 q  = U[min(k + half, m1 - 1)];
            int4 qn = U[min(k + 8 + half, m1 - 1)];
            float4 A = NR[q.x], Bv = NR[q.y], Cv = NR[q.z];
            while (k < m1) {
                const int kn = k + 8;
                const int4 qn2 = U[min(kn + 8 + half, m1 - 1)];
                const float4 An = NR[qn.x], Bn = NR[qn.y], Cn = NR[qn.z];  // prefetch
                const float h0 = __builtin_fmaf(A.x,  v0, __builtin_fmaf(A.y,  v1, A.z  * v2));
                const float h1 = __builtin_fmaf(Bv.x, v0, __builtin_fmaf(Bv.y, v1, Bv.z * v2));
                const float h2 = __builtin_fmaf(Cv.x, v0, __builtin_fmaf(Cv.y, v1, Cv.z * v2));
                const float h = fminf(h0, fminf(h1, h2));
                const float w = __int_as_float(q.w);
                if (k + half < m1) BODY(h, w)
                A = An; Bv = Bn; Cv = Cn;
                q = qn; qn = qn2; k = kn;
            }
        }
    }
#undef BODY

    __syncthreads();
    // flush rows 0..31 -> partial[block][s*32+t2]
    float* dst = partial + ((size_t)blockIdx.x << 10);
    for (int i = tid; i < SS * TT; i += 256) {
        const int s = i >> 5, t2 = i & 31;
        float acc = 0.0f;
#pragma unroll
        for (int wv = 0; wv < 4; ++wv)
            acc += hist[wv][s * 64 + t2] + hist[wv][s * 64 + t2 + 32];
        dst[i] = acc;
    }
}

// ---------- finish: one block per graph; reduce chunks + prefix over s ----------
__global__ __launch_bounds__(1024) void k_finish(
    const float* __restrict__ partial, float* __restrict__ out)
{
    __shared__ float tile[SS * TT];
    const int b   = blockIdx.x;
    const int tid = threadIdx.x;            // cell = s*32 + t
    float acc = 0.0f;
#pragma unroll
    for (int c = 0; c < NC; ++c) acc += partial[(((size_t)(c * NB + b)) << 10) + tid];
    tile[tid] = acc;
    __syncthreads();
    const int t = tid & 31, s = tid >> 5;
    float run = 0.0f;
    for (int sp = 0; sp <= s; ++sp) run += tile[(sp << 5) + t];
    out[((size_t)b << 10) + tid] = run;
}

extern "C" void kernel_launch(void* const* d_in, const int* in_sizes, int n_in,
                              void* d_out, int out_size, void* d_ws, size_t ws_size,
                              hipStream_t stream)
{
    const float* x     = (const float*)d_in[0];
    const float* nw    = (const float*)d_in[1];
    const float* v     = (const float*)d_in[2];
    const int*   ei    = (const int*)d_in[4];
    const int*   fc    = (const int*)d_in[5];
    const int*   batch = (const int*)d_in[6];
    float*       out   = (float*)d_out;

    const int Nn = in_sizes[1];
    const int E  = in_sizes[4] / 2;
    const int F  = in_sizes[5] / 3;

    auto align256 = [](size_t v_) { return (v_ + 255) & ~(size_t)255; };
    const size_t U_b    = align256((size_t)NB * UCAP * sizeof(int4));             // 4 MB
    const size_t part_b = align256((size_t)NC * NB * SS * TT * sizeof(float));    // 4 MB
    const size_t NR_b   = align256((size_t)Nn * sizeof(float4));                  // 0.8 MB

    int4*   U       = (int4*)d_ws;
    float*  partial = (float*)((char*)d_ws + U_b);
    float4* NR      = (float4*)((char*)d_ws + U_b + part_b);
    int*    cur     = (int*)((char*)d_ws + U_b + part_b + NR_b);  // [64]
    int*    ns      = cur + 64;                                   // [65]

    k_init <<<1, 256, 0, stream>>>(batch, cur, ns, Nn);
    k_build<<<NCNT + NRB, 256, 0, stream>>>(x, nw, ei, fc, batch, cur, U, NR, Nn, E, F);
    k_main2<<<NC * NB, 256, 0, stream>>>(x, nw, v, U, NR, ns, cur, partial);
    k_finish<<<NB, 1024, 0, stream>>>(partial, out);
}

// Round 20
// 37.068 us; speedup vs baseline: 2.8021x; 2.8021x over previous
//
#include <hip/hip_runtime.h>

// Problem constants: N=50000, E=100000, F=80000, B=64, S=32, T=32, D=3
#define NB      64
#define SS      32
#define TT      32
#define RADIUSF 1.1f
#define NC      16              // chunks per graph -> grid = 16*64 = 1024 = 4 blocks/CU
#define NROWS   34              // delta bins: s* in [0,32], s*+1 in [1,33]
#define NCNT    128             // blocks for build pass
#define BCAP    1440            // max EF items per build slice (180000/128 = 1407)
#define UCAP    4096            // per-graph capacity in U (mean 2812, >20 sigma headroom)

// ---------- k_init: zero reservation counters + node ranges ----------
__global__ __launch_bounds__(256) void k_init(
    const int* __restrict__ batch, int* __restrict__ cur,
    int* __restrict__ ns, int Nn)
{
    const int tid = threadIdx.x;
    if (tid < NB) cur[tid] = 0;
    if (tid <= NB) {
        int lo = 0, hi = Nn;
        while (lo < hi) { const int mid = (lo + hi) >> 1; if (batch[mid] < tid) lo = mid + 1; else hi = mid; }
        ns[tid] = lo;
    }
}

// ---------- k_build: LDS record cache + direct atomic reservation into U ----------
__global__ __launch_bounds__(256) void k_build(
    const float* __restrict__ nw, const int* __restrict__ ei,
    const int* __restrict__ fc, const int* __restrict__ batch,
    int* __restrict__ cur, int4* __restrict__ U, int E, int F)
{
    __shared__ int lc[NB];
    __shared__ int lb[NB];
    __shared__ int   r_i0[BCAP], r_i1[BCAP], r_i2[BCAP];
    __shared__ float r_w[BCAP];
    __shared__ unsigned char r_b[BCAP];
    const int tid = threadIdx.x;
    const int EF = E + F;

    if (tid < NB) lc[tid] = 0;
    __syncthreads();

    const int j0 = (int)((long long)EF * blockIdx.x / NCNT);
    const int j1 = (int)((long long)EF * (blockIdx.x + 1) / NCNT);
    // pass 1: gather once, stash record in LDS, count per bucket (LDS atomics)
    for (int j = j0 + tid, idx = tid; j < j1; j += 256, idx += 256) {
        int i0, i1, i2; float w;
        if (j < E) {
            i0 = ei[j]; i1 = ei[E + j]; i2 = i0;
            w = -fmaxf(nw[i0], nw[i1]);
        } else {
            const int f = j - E;
            i0 = fc[f]; i1 = fc[F + f]; i2 = fc[2 * F + f];
            w = fmaxf(nw[i0], fmaxf(nw[i1], nw[i2]));
        }
        const int b = batch[i0];
        r_i0[idx] = i0; r_i1[idx] = i1; r_i2[idx] = i2;
        r_w[idx] = w; r_b[idx] = (unsigned char)b;
        atomicAdd(&lc[b], 1);
    }
    __syncthreads();
    // reserve a contiguous run per bucket: ONE global atomic per (block,bucket)
    if (tid < NB) { const int c = lc[tid]; lb[tid] = c ? atomicAdd(&cur[tid], c) : 0; lc[tid] = 0; }
    __syncthreads();
    // pass 2: write from LDS records at reserved slots
    const int cnt = j1 - j0;
    for (int idx = tid; idx < cnt; idx += 256) {
        const int b = r_b[idx];
        const int r = atomicAdd(&lc[b], 1);
        U[(b << 12) + lb[b] + r] =
            make_int4(r_i0[idx], r_i1[idx], r_i2[idx], __float_as_int(r_w[idx]));
    }
}

// ---------- k_main2: (b,chunk) blocks; vec4 node loop; pipelined EF loop ----------
__global__ __launch_bounds__(256) void k_main2(
    const float* __restrict__ x, const float* __restrict__ nw,
    const float* __restrict__ v, const int4* __restrict__ U,
    const int* __restrict__ ns, const int* __restrict__ cur,
    float* __restrict__ partial)
{
    __shared__ float hist[4][NROWS * 64];

    const int tid  = threadIdx.x;
    const int wave = tid >> 6;
    const int lane = tid & 63;
    const int t    = lane & 31;
    const int half = lane >> 5;
    const int b     = blockIdx.x & 63;      // XCD-aligned: all chunks of b on XCD b%8
    const int chunk = blockIdx.x >> 6;

    float* H = hist[wave];
    for (int i = tid; i < 4 * NROWS * 64; i += 256) ((float*)hist)[i] = 0.0f;
    __syncthreads();

    // v column for this lane's theta (3 regs)
    const float v0 = v[t], v1 = v[TT + t], v2 = v[2 * TT + t];

    const float INV = 31.0f / 2.2f;
    const float DLT = 2.2f / 31.0f;

    // s* = rint((h+R)/step); sigma* = 1/(1+exp(500*(h - lin[s*])))
#define BODY(hv, wv)                                                        \
    {                                                                       \
        const float hr = hv + RADIUSF;                                      \
        float sf = rintf(hr * INV);                                         \
        sf = fminf(fmaxf(sf, 0.0f), 32.0f);                                 \
        const float t1 = __builtin_fmaf(sf, -DLT, hr);                      \
        const float Ee = __expf(500.0f * t1);                               \
        const float sg = __builtin_amdgcn_rcpf(1.0f + Ee);                  \
        const float dA = wv * sg;                                           \
        const float dB = wv - dA;                                           \
        float* p = H + (int)sf * 64 + lane;                                 \
        p[0]  += dA;                                                        \
        p[64] += dB;                                                        \
    }

    // ---- nodes of graph b: 4 nodes per half-iter via aligned float4 loads ----
    {
        const int g0 = ns[b], g1 = ns[b + 1];
        const int gc = g1 - g0;
        const int m0 = g0 + (int)(((long long)gc * chunk) / NC);
        const int m1 = g0 + (int)(((long long)gc * (chunk + 1)) / NC);
        const int gs = m0 & ~3;                       // 4-aligned base
        for (int g = gs + (wave * 2 + half) * 4; g < m1; g += 32) {
            if (g >= m0 && g + 4 <= m1) {             // fast aligned quad
                const float4* xp = (const float4*)(x + 3 * g);
                const float4 X0 = xp[0], X1 = xp[1], X2 = xp[2];
                const float4 W  = *(const float4*)(nw + g);
                const float ha = __builtin_fmaf(X0.x, v0, __builtin_fmaf(X0.y, v1, X0.z * v2));
                const float hb = __builtin_fmaf(X0.w, v0, __builtin_fmaf(X1.x, v1, X1.y * v2));
                const float hc = __builtin_fmaf(X1.z, v0, __builtin_fmaf(X1.w, v1, X2.x * v2));
                const float hd = __builtin_fmaf(X2.y, v0, __builtin_fmaf(X2.z, v1, X2.w * v2));
                BODY(ha, W.x) BODY(hb, W.y) BODY(hc, W.z) BODY(hd, W.w)
            } else {                                  // head/tail scalar
                const int n_lo = g < m0 ? m0 : g;
                const int n_hi = (g + 4 < m1 ? g + 4 : m1);
                for (int n = n_lo; n < n_hi; ++n) {
                    const float x0 = x[3 * n], x1 = x[3 * n + 1], x2 = x[3 * n + 2];
                    const float h = __builtin_fmaf(x0, v0, __builtin_fmaf(x1, v1, x2 * v2));
                    BODY(h, nw[n])
                }
            }
        }
    }

    // ---- edges+faces of graph b: software-pipelined (q depth-2, x depth-1) ----
    {
        const int g0 = b << 12;                       // b * UCAP
        const int gc = min(cur[b], UCAP);
        const int m0 = g0 + (int)(((long long)gc * chunk) / NC);
        const int m1 = g0 + (int)(((long long)gc * (chunk + 1)) / NC);
        int k = m0 + wave * 2;
        if (k < m1) {
            int4 q  = U[min(k + half, m1 - 1)];
            int4 qn = U[min(k + 8 + half, m1 - 1)];
            float a0 = x[3 * q.x], a1 = x[3 * q.x + 1], a2 = x[3 * q.x + 2];
            float b0 = x[3 * q.y], b1 = x[3 * q.y + 1], b2 = x[3 * q.y + 2];
            float c0 = x[3 * q.z], c1 = x[3 * q.z + 1], c2 = x[3 * q.z + 2];
            while (k < m1) {
                const int kn = k + 8;
                // issue next-next q and next x-loads before computing current
                const int4 qn2 = U[min(kn + 8 + half, m1 - 1)];
                const float na0 = x[3 * qn.x], na1 = x[3 * qn.x + 1], na2 = x[3 * qn.x + 2];
                const float nb0 = x[3 * qn.y], nb1 = x[3 * qn.y + 1], nb2 = x[3 * qn.y + 2];
                const float nc0 = x[3 * qn.z], nc1 = x[3 * qn.z + 1], nc2 = x[3 * qn.z + 2];
                // compute current
                const float h0 = __builtin_fmaf(a0, v0, __builtin_fmaf(a1, v1, a2 * v2));
                const float h1 = __builtin_fmaf(b0, v0, __builtin_fmaf(b1, v1, b2 * v2));
                const float h2 = __builtin_fmaf(c0, v0, __builtin_fmaf(c1, v1, c2 * v2));
                const float h = fminf(h0, fminf(h1, h2));
                const float w = __int_as_float(q.w);
                if (k + half < m1) BODY(h, w)
                // rotate
                a0 = na0; a1 = na1; a2 = na2;
                b0 = nb0; b1 = nb1; b2 = nb2;
                c0 = nc0; c1 = nc1; c2 = nc2;
                q = qn; qn = qn2; k = kn;
            }
        }
    }
#undef BODY

    __syncthreads();
    // flush rows 0..31 -> partial[block][s*32+t2]
    float* dst = partial + ((size_t)blockIdx.x << 10);
    for (int i = tid; i < SS * TT; i += 256) {
        const int s = i >> 5, t2 = i & 31;
        float acc = 0.0f;
#pragma unroll
        for (int wv = 0; wv < 4; ++wv)
            acc += hist[wv][s * 64 + t2] + hist[wv][s * 64 + t2 + 32];
        dst[i] = acc;
    }
}

// ---------- finish: one block per graph; reduce chunks + prefix over s ----------
__global__ __launch_bounds__(1024) void k_finish(
    const float* __restrict__ partial, float* __restrict__ out)
{
    __shared__ float tile[SS * TT];
    const int b   = blockIdx.x;
    const int tid = threadIdx.x;            // cell = s*32 + t
    float acc = 0.0f;
#pragma unroll
    for (int c = 0; c < NC; ++c) acc += partial[(((size_t)(c * NB + b)) << 10) + tid];
    tile[tid] = acc;
    __syncthreads();
    const int t = tid & 31, s = tid >> 5;
    float run = 0.0f;
    for (int sp = 0; sp <= s; ++sp) run += tile[(sp << 5) + t];
    out[((size_t)b << 10) + tid] = run;
}

extern "C" void kernel_launch(void* const* d_in, const int* in_sizes, int n_in,
                              void* d_out, int out_size, void* d_ws, size_t ws_size,
                              hipStream_t stream)
{
    const float* x     = (const float*)d_in[0];
    const float* nw    = (const float*)d_in[1];
    const float* v     = (const float*)d_in[2];
    const int*   ei    = (const int*)d_in[4];
    const int*   fc    = (const int*)d_in[5];
    const int*   batch = (const int*)d_in[6];
    float*       out   = (float*)d_out;

    const int Nn = in_sizes[1];
    const int E  = in_sizes[4] / 2;
    const int F  = in_sizes[5] / 3;

    auto align256 = [](size_t v_) { return (v_ + 255) & ~(size_t)255; };
    const size_t U_b    = align256((size_t)NB * UCAP * sizeof(int4));             // 4 MB
    const size_t part_b = align256((size_t)NC * NB * SS * TT * sizeof(float));    // 4 MB

    int4*  U       = (int4*)d_ws;
    float* partial = (float*)((char*)d_ws + U_b);
    int*   cur     = (int*)((char*)d_ws + U_b + part_b);          // [64]
    int*   ns      = cur + 64;                                    // [65]

    k_init <<<1, 256, 0, stream>>>(batch, cur, ns, Nn);
    k_build<<<NCNT, 256, 0, stream>>>(nw, ei, fc, batch, cur, U, E, F);
    k_main2<<<NC * NB, 256, 0, stream>>>(x, nw, v, U, ns, cur, partial);
    k_finish<<<NB, 1024, 0, stream>>>(partial, out);
}